// Round 1
// baseline (5676.826 us; speedup 1.0000x reference)
//
#include <hip/hip_runtime.h>

#define CC 128

static __device__ __forceinline__ unsigned fenc(float f){
  unsigned u = __float_as_uint(f);
  return (u & 0x80000000u) ? ~u : (u | 0x80000000u);
}
static __device__ __forceinline__ float fdec(unsigned u){
  unsigned v = (u & 0x80000000u) ? (u & 0x7fffffffu) : ~u;
  return __uint_as_float(v);
}
static __device__ __forceinline__ float lrelu(float v){ return v > 0.f ? v : 0.2f*v; }

// ---------------- GEMM: out[N,128] = (RELU?relu(in):in)[N,128] @ W[128,128]
template<bool RELU>
__global__ __launch_bounds__(256) void gemm128(const float* __restrict__ in,
                                               const float* __restrict__ W,
                                               float* __restrict__ out){
  __shared__ float4 xs4[32*33];   // 32 rows, stride 33 float4 (pad kills bank conflicts)
  const int tid = threadIdx.x;
  const long row0 = (long)blockIdx.x * 32;
  const float4* in4 = (const float4*)(in + row0*CC);
  #pragma unroll
  for (int i=0;i<4;i++){
    int f = tid + i*256;            // f in [0,1024): row f/32, c4 f%32
    float4 v = in4[f];
    if (RELU){ v.x=fmaxf(v.x,0.f); v.y=fmaxf(v.y,0.f); v.z=fmaxf(v.z,0.f); v.w=fmaxf(v.w,0.f); }
    xs4[(f>>5)*33 + (f&31)] = v;
  }
  __syncthreads();
  const int tc = tid & 31;          // cols tc*4..+3
  const int tr = tid >> 5;          // rows tr*4..+3
  const float4* W4 = (const float4*)W;
  float acc[4][4] = {};
  #pragma unroll 2
  for (int kq=0; kq<32; kq++){
    float4 w0 = W4[(kq*4+0)*32 + tc];
    float4 w1 = W4[(kq*4+1)*32 + tc];
    float4 w2 = W4[(kq*4+2)*32 + tc];
    float4 w3 = W4[(kq*4+3)*32 + tc];
    #pragma unroll
    for (int i=0;i<4;i++){
      float4 xv = xs4[(tr*4+i)*33 + kq];
      acc[i][0] += xv.x*w0.x + xv.y*w1.x + xv.z*w2.x + xv.w*w3.x;
      acc[i][1] += xv.x*w0.y + xv.y*w1.y + xv.z*w2.y + xv.w*w3.y;
      acc[i][2] += xv.x*w0.z + xv.y*w1.z + xv.z*w2.z + xv.w*w3.z;
      acc[i][3] += xv.x*w0.w + xv.y*w1.w + xv.z*w2.w + xv.w*w3.w;
    }
  }
  float4* out4 = (float4*)(out + row0*CC);
  #pragma unroll
  for (int i=0;i<4;i++)
    out4[(tr*4+i)*32 + tc] = make_float4(acc[i][0],acc[i][1],acc[i][2],acc[i][3]);
}

// ---------------- per-row dot with two vectors: as[i]=xw[i]·a1, ad[i]=xw[i]·a2
__global__ __launch_bounds__(256) void rowdot2(const float* __restrict__ xw,
                                               const float* __restrict__ a1,
                                               const float* __restrict__ a2,
                                               float* __restrict__ as_, float* __restrict__ ad_){
  const int lane = threadIdx.x & 63;
  const long row = (long)blockIdx.x*4 + (threadIdx.x >> 6);
  float2 v  = ((const float2*)(xw + row*CC))[lane];
  float2 w1 = ((const float2*)a1)[lane];
  float2 w2 = ((const float2*)a2)[lane];
  float s1 = v.x*w1.x + v.y*w1.y;
  float s2 = v.x*w2.x + v.y*w2.y;
  #pragma unroll
  for (int off=32; off; off>>=1){
    s1 += __shfl_xor(s1, off);
    s2 += __shfl_xor(s2, off);
  }
  if (lane==0){ as_[row]=s1; ad_[row]=s2; }
}

// ---------------- GAT segment softmax pieces
__global__ void gat_init(const float* __restrict__ as_, const float* __restrict__ ad_,
                         unsigned* __restrict__ emx, float* __restrict__ den, int N){
  int i = blockIdx.x*256 + threadIdx.x;
  if (i < N){
    float e = lrelu(as_[i] + ad_[i]);   // self loop
    emx[i] = fenc(e);
    den[i] = 0.f;
  }
}

__global__ void gat_edge_max(const int* __restrict__ ei, const float* __restrict__ as_,
                             const float* __restrict__ ad_, unsigned* __restrict__ emx, int E){
  int e = blockIdx.x*256 + threadIdx.x;
  if (e < E){
    int s = ei[e], d = ei[E + e];
    float v = lrelu(as_[s] + ad_[d]);
    atomicMax(&emx[d], fenc(v));
  }
}

__global__ void gat_alpha(const int* __restrict__ ei, const float* __restrict__ as_,
                          const float* __restrict__ ad_, const unsigned* __restrict__ emx,
                          float* __restrict__ den, float* __restrict__ alpha, int E, int N){
  int idx = blockIdx.x*256 + threadIdx.x;
  if (idx >= E + N) return;
  int s, d;
  if (idx < E){ s = ei[idx]; d = ei[E + idx]; }
  else { s = idx - E; d = s; }
  float v = lrelu(as_[s] + ad_[d]);
  float p = __expf(v - fdec(emx[d]));
  alpha[idx] = p;
  atomicAdd(&den[d], p);
}

__global__ void gat_alpha_norm(const int* __restrict__ ei, const float* __restrict__ den,
                               float* __restrict__ alpha, int E, int N){
  int idx = blockIdx.x*256 + threadIdx.x;
  if (idx >= E + N) return;
  int d = (idx < E) ? ei[E + idx] : (idx - E);
  alpha[idx] = alpha[idx] / den[d];
}

// out[i] = b + alpha_self * xw[i]
__global__ void gat_out_init(const float* __restrict__ xw, const float* __restrict__ alpha,
                             const float* __restrict__ b, float* __restrict__ out, int E, int N){
  int t = blockIdx.x*256 + threadIdx.x;
  int i = t >> 5, c4 = t & 31;
  if (i >= N) return;
  float a = alpha[E + i];
  float4 v  = ((const float4*)(xw + (long)i*CC))[c4];
  float4 bb = ((const float4*)b)[c4];
  ((float4*)(out + (long)i*CC))[c4] =
      make_float4(bb.x + a*v.x, bb.y + a*v.y, bb.z + a*v.z, bb.w + a*v.w);
}

// out[dst] += alpha_e * xw[src]   (32 threads per edge, float4 each)
__global__ void gat_scatter(const int* __restrict__ ei, const float* __restrict__ xw,
                            const float* __restrict__ alpha, float* __restrict__ out, int E){
  long t = (long)blockIdx.x*256 + threadIdx.x;
  int e = (int)(t >> 5), c4 = (int)(t & 31);
  if (e >= E) return;
  int s = ei[e], d = ei[E + e];
  float a = alpha[e];
  float4 v = ((const float4*)(xw + (long)s*CC))[c4];
  float* o = out + (long)d*CC + c4*4;
  atomicAdd(o+0, a*v.x);
  atomicAdd(o+1, a*v.y);
  atomicAdd(o+2, a*v.z);
  atomicAdd(o+3, a*v.w);
}

// ---------------- flash attention (fp32): out = softmax(q@h^T/sqrt(128)) @ h
__global__ __launch_bounds__(256) void attn_flash(const float* __restrict__ q,
                                                  const float* __restrict__ h,
                                                  float* __restrict__ out, int n){
  __shared__ float4 qs4[64*33];
  __shared__ float4 hs4[32*33];
  __shared__ __align__(16) float ps[64*36];
  const int tid = threadIdx.x;
  const long qr0 = (long)blockIdx.x * 64;
  const float4* q4 = (const float4*)(q + qr0*CC);
  #pragma unroll
  for (int i=0;i<8;i++){
    int f = tid + i*256;
    qs4[(f>>5)*33 + (f&31)] = q4[f];
  }
  const int tc = tid & 15;
  const int tr = tid >> 4;
  float m[4], l[4];
  #pragma unroll
  for (int i=0;i<4;i++){ m[i] = -3.0e38f; l[i] = 0.f; }
  float acc[4][8];
  #pragma unroll
  for (int i=0;i<4;i++)
    #pragma unroll
    for (int j=0;j<8;j++) acc[i][j] = 0.f;
  const float rs = 0.088388347648318447f;   // 1/sqrt(128)
  const float4* ps4 = (const float4*)ps;
  const int nt = n >> 5;
  for (int kt=0; kt<nt; kt++){
    __syncthreads();                           // previous PV done
    const float4* h4 = (const float4*)(h + (long)kt*32*CC);
    #pragma unroll
    for (int i=0;i<4;i++){
      int f = tid + i*256;
      hs4[(f>>5)*33 + (f&31)] = h4[f];
    }
    __syncthreads();                           // hs ready
    // S = q(64x128) @ h_tile^T(128x32); this thread: rows tr*4..+3, cols {tc, tc+16}
    float s0[4] = {0.f,0.f,0.f,0.f}, s1[4] = {0.f,0.f,0.f,0.f};
    #pragma unroll 4
    for (int kq=0; kq<32; kq++){
      float4 h0 = hs4[tc*33 + kq];
      float4 h1 = hs4[(tc+16)*33 + kq];
      #pragma unroll
      for (int i=0;i<4;i++){
        float4 qv = qs4[(tr*4+i)*33 + kq];
        s0[i] += qv.x*h0.x + qv.y*h0.y + qv.z*h0.z + qv.w*h0.w;
        s1[i] += qv.x*h1.x + qv.y*h1.y + qv.z*h1.z + qv.w*h1.w;
      }
    }
    // online softmax over the 16 lanes sharing each row
    #pragma unroll
    for (int i=0;i<4;i++){
      float v0 = s0[i]*rs, v1 = s1[i]*rs;
      float tm = fmaxf(v0, v1);
      #pragma unroll
      for (int off=1; off<16; off<<=1) tm = fmaxf(tm, __shfl_xor(tm, off));
      float mn = fmaxf(m[i], tm);
      float fr = __expf(m[i] - mn);
      float p0 = __expf(v0 - mn);
      float p1 = __expf(v1 - mn);
      float ts = p0 + p1;
      #pragma unroll
      for (int off=1; off<16; off<<=1) ts += __shfl_xor(ts, off);
      l[i] = l[i]*fr + ts;
      m[i] = mn;
      #pragma unroll
      for (int j=0;j<8;j++) acc[i][j] *= fr;
      ps[(tr*4+i)*36 + tc]      = p0;
      ps[(tr*4+i)*36 + tc + 16] = p1;
    }
    __syncthreads();                           // ps ready
    // PV: acc(rows tr*4..+3, cols tc*8..+7) += P(64x32) @ h_tile(32x128)
    #pragma unroll 2
    for (int kv4=0; kv4<8; kv4++){
      float hvf[4][8];
      #pragma unroll
      for (int kk=0;kk<4;kk++){
        float4 a0 = hs4[(kv4*4+kk)*33 + tc*2+0];
        float4 a1 = hs4[(kv4*4+kk)*33 + tc*2+1];
        hvf[kk][0]=a0.x; hvf[kk][1]=a0.y; hvf[kk][2]=a0.z; hvf[kk][3]=a0.w;
        hvf[kk][4]=a1.x; hvf[kk][5]=a1.y; hvf[kk][6]=a1.z; hvf[kk][7]=a1.w;
      }
      #pragma unroll
      for (int i=0;i<4;i++){
        float4 pv = ps4[(tr*4+i)*9 + kv4];
        #pragma unroll
        for (int j=0;j<8;j++)
          acc[i][j] += pv.x*hvf[0][j] + pv.y*hvf[1][j] + pv.z*hvf[2][j] + pv.w*hvf[3][j];
      }
    }
  }
  float4* out4 = (float4*)(out + qr0*CC);
  #pragma unroll
  for (int i=0;i<4;i++){
    float inv = 1.f / l[i];
    out4[(tr*4+i)*32 + tc*2]     = make_float4(acc[i][0]*inv, acc[i][1]*inv, acc[i][2]*inv, acc[i][3]*inv);
    out4[(tr*4+i)*32 + tc*2 + 1] = make_float4(acc[i][4]*inv, acc[i][5]*inv, acc[i][6]*inv, acc[i][7]*inv);
  }
}

// ---------------- residual + bias + LayerNorm
__global__ __launch_bounds__(256) void residual_ln(const float* __restrict__ att,
                                                   const float* __restrict__ x,
                                                   const float* __restrict__ ab,
                                                   const float* __restrict__ g,
                                                   const float* __restrict__ be,
                                                   float* __restrict__ out, int N){
  const int lane = threadIdx.x & 63;
  const long row = (long)blockIdx.x*4 + (threadIdx.x >> 6);
  float2 v  = ((const float2*)(att + row*CC))[lane];
  float2 xb = ((const float2*)(x   + row*CC))[lane];
  float2 bb = ((const float2*)ab)[lane];
  float a0 = v.x + bb.x + xb.x;
  float a1 = v.y + bb.y + xb.y;
  float s = a0 + a1, ss = a0*a0 + a1*a1;
  #pragma unroll
  for (int off=32; off; off>>=1){ s += __shfl_xor(s,off); ss += __shfl_xor(ss,off); }
  float mu  = s * (1.f/128.f);
  float var = ss * (1.f/128.f) - mu*mu;
  float rstd = rsqrtf(var + 1e-5f);
  float2 gg = ((const float2*)g)[lane];
  float2 b2 = ((const float2*)be)[lane];
  float2 r;
  r.x = (a0 - mu)*rstd*gg.x + b2.x;
  r.y = (a1 - mu)*rstd*gg.y + b2.y;
  ((float2*)(out + row*CC))[lane] = r;
}

extern "C" void kernel_launch(void* const* d_in, const int* in_sizes, int n_in,
                              void* d_out, int out_size, void* d_ws, size_t ws_size,
                              hipStream_t stream) {
  const float* x   = (const float*)d_in[0];
  const int*   ei  = (const int*)d_in[1];
  // d_in[2] edge_attr — unused by the reference (GATConv without edge_dim)
  const float* W1  = (const float*)d_in[3];
  const float* a_s1= (const float*)d_in[4];
  const float* a_d1= (const float*)d_in[5];
  const float* b1  = (const float*)d_in[6];
  const float* W2  = (const float*)d_in[7];
  const float* a_s2= (const float*)d_in[8];
  const float* a_d2= (const float*)d_in[9];
  const float* b2  = (const float*)d_in[10];
  const float* Wa  = (const float*)d_in[11];
  const float* ab  = (const float*)d_in[12];
  const float* g   = (const float*)d_in[13];
  const float* be  = (const float*)d_in[14];
  float* out = (float*)d_out;

  const int N = in_sizes[0] / CC;
  const int E = in_sizes[1] / 2;

  float* bufA = (float*)d_ws;                    // N*C   (xw / q)
  float* bufB = bufA + (size_t)N*CC;             // N*C   (h)
  float* bufC = bufB + (size_t)N*CC;             // N*C   (attn out)
  float* as_  = bufC + (size_t)N*CC;             // N
  float* ad_  = as_ + N;                         // N
  float* den  = ad_ + N;                         // N
  unsigned* emx = (unsigned*)(den + N);          // N
  float* alpha = (float*)(emx + N);              // E+N

  dim3 B(256);
  const int gEN = (E + N + 255)/256;

  // ---- GAT layer 1: bufB = gat(x) + b1   (relu deferred into next gemm)
  gemm128<false><<<N/32, B, 0, stream>>>(x, W1, bufA);
  rowdot2<<<N/4, B, 0, stream>>>(bufA, a_s1, a_d1, as_, ad_);
  gat_init<<<(N+255)/256, B, 0, stream>>>(as_, ad_, emx, den, N);
  gat_edge_max<<<(E+255)/256, B, 0, stream>>>(ei, as_, ad_, emx, E);
  gat_alpha<<<gEN, B, 0, stream>>>(ei, as_, ad_, emx, den, alpha, E, N);
  gat_alpha_norm<<<gEN, B, 0, stream>>>(ei, den, alpha, E, N);
  gat_out_init<<<N/8, B, 0, stream>>>(bufA, alpha, b1, bufB, E, N);
  gat_scatter<<<E/8, B, 0, stream>>>(ei, bufA, alpha, bufB, E);

  // ---- GAT layer 2: bufB = gat(relu(bufB)) + b2
  gemm128<true><<<N/32, B, 0, stream>>>(bufB, W2, bufA);
  rowdot2<<<N/4, B, 0, stream>>>(bufA, a_s2, a_d2, as_, ad_);
  gat_init<<<(N+255)/256, B, 0, stream>>>(as_, ad_, emx, den, N);
  gat_edge_max<<<(E+255)/256, B, 0, stream>>>(ei, as_, ad_, emx, E);
  gat_alpha<<<gEN, B, 0, stream>>>(ei, as_, ad_, emx, den, alpha, E, N);
  gat_alpha_norm<<<gEN, B, 0, stream>>>(ei, den, alpha, E, N);
  gat_out_init<<<N/8, B, 0, stream>>>(bufA, alpha, b2, bufB, E, N);
  gat_scatter<<<E/8, B, 0, stream>>>(ei, bufA, alpha, bufB, E);

  // ---- dense temporal attention: bufC = softmax(q@h^T/sqrt(C)) @ h
  gemm128<false><<<N/32, B, 0, stream>>>(bufB, Wa, bufA);   // q = h @ att_weight
  attn_flash<<<N/64, B, 0, stream>>>(bufA, bufB, bufC, N);

  // ---- + att_bias + residual + LayerNorm
  residual_ln<<<N/4, B, 0, stream>>>(bufC, x, ab, g, be, out, N);
}

// Round 2
// 2329.776 us; speedup vs baseline: 2.4366x; 2.4366x over previous
//
#include <hip/hip_runtime.h>

#define CC 128

typedef __attribute__((ext_vector_type(8))) short bf16x8;
typedef __attribute__((ext_vector_type(4))) float f32x4;

static __device__ __forceinline__ unsigned fenc(float f){
  unsigned u = __float_as_uint(f);
  return (u & 0x80000000u) ? ~u : (u | 0x80000000u);
}
static __device__ __forceinline__ float fdec(unsigned u){
  unsigned v = (u & 0x80000000u) ? (u & 0x7fffffffu) : ~u;
  return __uint_as_float(v);
}
static __device__ __forceinline__ float lrelu(float v){ return v > 0.f ? v : 0.2f*v; }
static __device__ __forceinline__ unsigned short f2bf(float f){
  unsigned u = __float_as_uint(f);
  unsigned r = (u + 0x7fffu + ((u >> 16) & 1u)) >> 16;
  return (unsigned short)r;
}
static __device__ __forceinline__ float bf2f(unsigned short s){
  return __uint_as_float(((unsigned)s) << 16);
}

// ---------------- GEMM: out[N,128] = (RELU?relu(in):in)[N,128] @ W[128,128]
template<bool RELU, bool OBF16>
__global__ __launch_bounds__(256) void gemm128(const float* __restrict__ in,
                                               const float* __restrict__ W,
                                               void* __restrict__ outv){
  __shared__ float4 xs4[32*33];
  const int tid = threadIdx.x;
  const long row0 = (long)blockIdx.x * 32;
  const float4* in4 = (const float4*)(in + row0*CC);
  #pragma unroll
  for (int i=0;i<4;i++){
    int f = tid + i*256;
    float4 v = in4[f];
    if (RELU){ v.x=fmaxf(v.x,0.f); v.y=fmaxf(v.y,0.f); v.z=fmaxf(v.z,0.f); v.w=fmaxf(v.w,0.f); }
    xs4[(f>>5)*33 + (f&31)] = v;
  }
  __syncthreads();
  const int tc = tid & 31;
  const int tr = tid >> 5;
  const float4* W4 = (const float4*)W;
  float acc[4][4] = {};
  #pragma unroll 2
  for (int kq=0; kq<32; kq++){
    float4 w0 = W4[(kq*4+0)*32 + tc];
    float4 w1 = W4[(kq*4+1)*32 + tc];
    float4 w2 = W4[(kq*4+2)*32 + tc];
    float4 w3 = W4[(kq*4+3)*32 + tc];
    #pragma unroll
    for (int i=0;i<4;i++){
      float4 xv = xs4[(tr*4+i)*33 + kq];
      acc[i][0] += xv.x*w0.x + xv.y*w1.x + xv.z*w2.x + xv.w*w3.x;
      acc[i][1] += xv.x*w0.y + xv.y*w1.y + xv.z*w2.y + xv.w*w3.y;
      acc[i][2] += xv.x*w0.z + xv.y*w1.z + xv.z*w2.z + xv.w*w3.z;
      acc[i][3] += xv.x*w0.w + xv.y*w1.w + xv.z*w2.w + xv.w*w3.w;
    }
  }
  if (OBF16){
    unsigned short* out = (unsigned short*)outv;
    #pragma unroll
    for (int i=0;i<4;i++){
      ushort4 o; o.x=f2bf(acc[i][0]); o.y=f2bf(acc[i][1]); o.z=f2bf(acc[i][2]); o.w=f2bf(acc[i][3]);
      *(ushort4*)&out[(row0 + tr*4 + i)*CC + tc*4] = o;
    }
  } else {
    float4* out4 = (float4*)((float*)outv + row0*CC);
    #pragma unroll
    for (int i=0;i<4;i++)
      out4[(tr*4+i)*32 + tc] = make_float4(acc[i][0],acc[i][1],acc[i][2],acc[i][3]);
  }
}

// ---------------- per-row dot with two vectors
__global__ __launch_bounds__(256) void rowdot2(const float* __restrict__ xw,
                                               const float* __restrict__ a1,
                                               const float* __restrict__ a2,
                                               float* __restrict__ as_, float* __restrict__ ad_){
  const int lane = threadIdx.x & 63;
  const long row = (long)blockIdx.x*4 + (threadIdx.x >> 6);
  float2 v  = ((const float2*)(xw + row*CC))[lane];
  float2 w1 = ((const float2*)a1)[lane];
  float2 w2 = ((const float2*)a2)[lane];
  float s1 = v.x*w1.x + v.y*w1.y;
  float s2 = v.x*w2.x + v.y*w2.y;
  #pragma unroll
  for (int off=32; off; off>>=1){
    s1 += __shfl_xor(s1, off);
    s2 += __shfl_xor(s2, off);
  }
  if (lane==0){ as_[row]=s1; ad_[row]=s2; }
}

// ---------------- GAT segment softmax pieces
__global__ void gat_init(const float* __restrict__ as_, const float* __restrict__ ad_,
                         unsigned* __restrict__ emx, float* __restrict__ den, int N){
  int i = blockIdx.x*256 + threadIdx.x;
  if (i < N){
    float e = lrelu(as_[i] + ad_[i]);
    emx[i] = fenc(e);
    den[i] = 0.f;
  }
}

__global__ void gat_edge_max(const int* __restrict__ ei, const float* __restrict__ as_,
                             const float* __restrict__ ad_, unsigned* __restrict__ emx, int E){
  int e = blockIdx.x*256 + threadIdx.x;
  if (e < E){
    int s = ei[e], d = ei[E + e];
    float v = lrelu(as_[s] + ad_[d]);
    atomicMax(&emx[d], fenc(v));
  }
}

__global__ void gat_alpha(const int* __restrict__ ei, const float* __restrict__ as_,
                          const float* __restrict__ ad_, const unsigned* __restrict__ emx,
                          float* __restrict__ den, float* __restrict__ alpha, int E, int N){
  int idx = blockIdx.x*256 + threadIdx.x;
  if (idx >= E + N) return;
  int s, d;
  if (idx < E){ s = ei[idx]; d = ei[E + idx]; }
  else { s = idx - E; d = s; }
  float v = lrelu(as_[s] + ad_[d]);
  float p = __expf(v - fdec(emx[d]));
  alpha[idx] = p;
  atomicAdd(&den[d], p);
}

__global__ void gat_alpha_norm(const int* __restrict__ ei, const float* __restrict__ den,
                               float* __restrict__ alpha, int E, int N){
  int idx = blockIdx.x*256 + threadIdx.x;
  if (idx >= E + N) return;
  int d = (idx < E) ? ei[E + idx] : (idx - E);
  alpha[idx] = alpha[idx] / den[d];
}

__global__ void gat_out_init(const float* __restrict__ xw, const float* __restrict__ alpha,
                             const float* __restrict__ b, float* __restrict__ out, int E, int N){
  int t = blockIdx.x*256 + threadIdx.x;
  int i = t >> 5, c4 = t & 31;
  if (i >= N) return;
  float a = alpha[E + i];
  float4 v  = ((const float4*)(xw + (long)i*CC))[c4];
  float4 bb = ((const float4*)b)[c4];
  ((float4*)(out + (long)i*CC))[c4] =
      make_float4(bb.x + a*v.x, bb.y + a*v.y, bb.z + a*v.z, bb.w + a*v.w);
}

__global__ void gat_scatter(const int* __restrict__ ei, const float* __restrict__ xw,
                            const float* __restrict__ alpha, float* __restrict__ out, int E){
  long t = (long)blockIdx.x*256 + threadIdx.x;
  int e = (int)(t >> 5), c4 = (int)(t & 5*0 + 31);
  if (e >= E) return;
  int s = ei[e], d = ei[E + e];
  float a = alpha[e];
  float4 v = ((const float4*)(xw + (long)s*CC))[c4];
  float* o = out + (long)d*CC + c4*4;
  atomicAdd(o+0, a*v.x);
  atomicAdd(o+1, a*v.y);
  atomicAdd(o+2, a*v.z);
  atomicAdd(o+3, a*v.w);
}

// ---------------- h (f32) -> Hb (bf16 row-major) + HTb (bf16 transposed [C][N])
__global__ __launch_bounds__(256) void convert_ht(const float* __restrict__ h,
                                                  unsigned short* __restrict__ Hb,
                                                  unsigned short* __restrict__ HTb, int N){
  __shared__ unsigned short t[64][72];
  const int tid = threadIdx.x;
  const int n0 = blockIdx.x*64, c0 = blockIdx.y*64;
  #pragma unroll
  for (int i=0;i<4;i++){
    int f = tid + i*256;
    int row = f>>4, c4 = f&15;
    float4 v = *(const float4*)&h[(size_t)(n0+row)*CC + c0 + c4*4];
    ushort4 b; b.x=f2bf(v.x); b.y=f2bf(v.y); b.z=f2bf(v.z); b.w=f2bf(v.w);
    *(ushort4*)&Hb[(size_t)(n0+row)*CC + c0 + c4*4] = b;
    *(ushort4*)&t[row][c4*4] = b;
  }
  __syncthreads();
  #pragma unroll
  for (int i=0;i<4;i++){
    int f = tid + i*256;
    int c = f>>4, n4 = f&15;
    ushort4 b;
    b.x = t[n4*4+0][c]; b.y = t[n4*4+1][c]; b.z = t[n4*4+2][c]; b.w = t[n4*4+3][c];
    *(ushort4*)&HTb[(size_t)(c0+c)*N + n0 + n4*4] = b;
  }
}

// ---------------- MFMA flash attention (bf16), KV-split with normalized partials
// S^T = H_tile(64x128) @ Q^T ; online softmax per q-column ; O^T += HT_tile @ P^T
__global__ __launch_bounds__(256,2) void attn_mfma(
    const unsigned short* __restrict__ Qb, const unsigned short* __restrict__ Hb,
    const unsigned short* __restrict__ HTb,
    unsigned short* __restrict__ opLo, unsigned short* __restrict__ opHi,
    float* __restrict__ ml, int N, int nsplit){
  __shared__ uint4 SH[16*64];    // S-phase H fragments, fragment-ordered
  __shared__ uint4 STl[16*64];   // PV-phase HT fragments
  __shared__ uint4 PT[4*4*64];   // per-wave P^T fragments (4 frags x 64 lanes)

  const int tid = threadIdx.x;
  const int lane = tid & 63, w = tid >> 6;
  const int g = lane >> 4, c15 = lane & 15;
  const int qb0 = blockIdx.x * 128;
  const int split = blockIdx.y;
  const int keysPerSplit = N / nsplit;
  const int key00 = split * keysPerSplit;
  const int ntiles = keysPerSplit >> 6;
  const float RS = 0.088388347648318447f;  // 1/sqrt(128)

  // Q fragments (B-operand layout): lane holds Q[qrow][ks*32 + g*8 .. +7]
  bf16x8 qf[2][4];
  const int qrow_base = qb0 + w*32;
  #pragma unroll
  for (int qt=0; qt<2; qt++)
    #pragma unroll
    for (int ks=0; ks<4; ks++)
      qf[qt][ks] = *(const bf16x8*)&Qb[(size_t)(qrow_base + qt*16 + c15)*CC + ks*32 + g*8];

  f32x4 zero4 = {0.f,0.f,0.f,0.f};
  f32x4 acc_o[8][2];
  #pragma unroll
  for (int a=0;a<8;a++){ acc_o[a][0]=zero4; acc_o[a][1]=zero4; }
  float m_[2] = {-3.0e38f, -3.0e38f};
  float l_[2] = {0.f, 0.f};

  // LDS target units for staging (constant per thread)
  int shU[4], stU[4];
  #pragma unroll
  for (int i=0;i<4;i++){
    int f = tid + i*256;
    int key = f>>4, c8 = f&15;            // SH: chunk = Hb[key][c8*8..+7]
    shU[i] = ((key>>4)*4 + (c8>>2))*64 + (c8&3)*16 + (key&15);
    int c = f>>3, k8 = f&7;               // ST: chunk = HTb[c][k8*8..+7]
    stU[i] = ((c>>4)*2 + (k8>>2))*64 + (k8&3)*16 + (c&15);
  }

  uint4 G[8];
  {
    const unsigned short* hb = Hb + (size_t)key00*CC;
    const unsigned short* ht = HTb + key00;
    #pragma unroll
    for (int i=0;i<4;i++){
      int f = tid + i*256;
      G[i]   = *(const uint4*)&hb[(size_t)(f>>4)*CC + (f&15)*8];
      G[4+i] = *(const uint4*)&ht[(size_t)(f>>3)*N + (f&7)*8];
    }
  }

  for (int t=0; t<ntiles; t++){
    __syncthreads();                       // previous tile's compute done
    #pragma unroll
    for (int i=0;i<4;i++) SH[shU[i]]  = G[i];
    #pragma unroll
    for (int i=0;i<4;i++) STl[stU[i]] = G[4+i];
    if (t+1 < ntiles){
      const unsigned short* hb = Hb + (size_t)(key00 + (t+1)*64)*CC;
      const unsigned short* ht = HTb + key00 + (t+1)*64;
      #pragma unroll
      for (int i=0;i<4;i++){
        int f = tid + i*256;
        G[i]   = *(const uint4*)&hb[(size_t)(f>>4)*CC + (f&15)*8];
        G[4+i] = *(const uint4*)&ht[(size_t)(f>>3)*N + (f&7)*8];
      }
    }
    __syncthreads();                       // staged tile visible

    // ---- S phase: accs[kt][qt] = S^T tile (16 keys x 16 q)
    f32x4 accs[4][2];
    #pragma unroll
    for (int kt=0; kt<4; kt++){ accs[kt][0]=zero4; accs[kt][1]=zero4; }
    #pragma unroll
    for (int kt=0; kt<4; kt++)
      #pragma unroll
      for (int ks=0; ks<4; ks++){
        bf16x8 hf = *(const bf16x8*)&SH[(kt*4+ks)*64 + lane];
        accs[kt][0] = __builtin_amdgcn_mfma_f32_16x16x32_bf16(hf, qf[0][ks], accs[kt][0], 0,0,0);
        accs[kt][1] = __builtin_amdgcn_mfma_f32_16x16x32_bf16(hf, qf[1][ks], accs[kt][1], 0,0,0);
      }

    // ---- online softmax per q-column (per lane), P = exp in place
    float fr[2];
    #pragma unroll
    for (int qt=0; qt<2; qt++){
      float tm = -3.0e38f;
      #pragma unroll
      for (int kt=0; kt<4; kt++)
        #pragma unroll
        for (int r=0; r<4; r++) tm = fmaxf(tm, accs[kt][qt][r]);
      tm *= RS;
      tm = fmaxf(tm, __shfl_xor(tm, 16));
      tm = fmaxf(tm, __shfl_xor(tm, 32));
      float mn = fmaxf(m_[qt], tm);
      fr[qt] = __expf(m_[qt] - mn);
      m_[qt] = mn;
      float ps = 0.f;
      #pragma unroll
      for (int kt=0; kt<4; kt++)
        #pragma unroll
        for (int r=0; r<4; r++){
          float p = __expf(accs[kt][qt][r]*RS - mn);
          accs[kt][qt][r] = p;
          ps += p;
        }
      ps += __shfl_xor(ps, 16);
      ps += __shfl_xor(ps, 32);
      l_[qt] = l_[qt]*fr[qt] + ps;
    }
    #pragma unroll
    for (int a=0;a<8;a++){
      #pragma unroll
      for (int qt=0; qt<2; qt++){
        acc_o[a][qt][0]*=fr[qt]; acc_o[a][qt][1]*=fr[qt];
        acc_o[a][qt][2]*=fr[qt]; acc_o[a][qt][3]*=fr[qt];
      }
    }

    // ---- P^T -> fragment-order LDS (per-wave region), then read as B-frags
    unsigned short* pt16 = (unsigned short*)&PT[w*256];
    #pragma unroll
    for (int kt=0; kt<4; kt++)
      #pragma unroll
      for (int qt=0; qt<2; qt++){
        ushort4 pk;
        pk.x = f2bf(accs[kt][qt][0]); pk.y = f2bf(accs[kt][qt][1]);
        pk.z = f2bf(accs[kt][qt][2]); pk.w = f2bf(accs[kt][qt][3]);
        int addr = ((kt>>1)*2 + qt)*512 + (((kt&1)*2 + (g>>1))*16 + c15)*8 + (g&1)*4;
        *(ushort4*)&pt16[addr] = pk;
      }
    bf16x8 ptf[2][2];
    const uint4* ptv = &PT[w*256];
    #pragma unroll
    for (int ks2=0; ks2<2; ks2++)
      #pragma unroll
      for (int qt=0; qt<2; qt++)
        ptf[ks2][qt] = *(const bf16x8*)&ptv[(ks2*2+qt)*64 + lane];

    // ---- PV: O^T[ct2][qt] += HT_frag @ P^T_frag
    #pragma unroll
    for (int ct2=0; ct2<8; ct2++)
      #pragma unroll
      for (int ks2=0; ks2<2; ks2++){
        bf16x8 hf = *(const bf16x8*)&STl[(ct2*2+ks2)*64 + lane];
        acc_o[ct2][0] = __builtin_amdgcn_mfma_f32_16x16x32_bf16(hf, ptf[ks2][0], acc_o[ct2][0], 0,0,0);
        acc_o[ct2][1] = __builtin_amdgcn_mfma_f32_16x16x32_bf16(hf, ptf[ks2][1], acc_o[ct2][1], 0,0,0);
      }
  }

  // ---- epilogue: normalized bf16 partials + (m,l)
  unsigned short* opBase = (split < 2) ? (opLo + (size_t)split*N*CC)
                                       : (opHi + (size_t)(split-2)*N*CC);
  #pragma unroll
  for (int qt=0; qt<2; qt++){
    float inv = 1.f / l_[qt];
    int qrow = qrow_base + qt*16 + c15;
    #pragma unroll
    for (int ct2=0; ct2<8; ct2++){
      ushort4 o;
      o.x = f2bf(acc_o[ct2][qt][0]*inv); o.y = f2bf(acc_o[ct2][qt][1]*inv);
      o.z = f2bf(acc_o[ct2][qt][2]*inv); o.w = f2bf(acc_o[ct2][qt][3]*inv);
      *(ushort4*)&opBase[(size_t)qrow*CC + ct2*16 + g*4] = o;
    }
    if (g == 0)
      ((float2*)ml)[(size_t)split*N + qrow] = make_float2(m_[qt], l_[qt]);
  }
}

// ---------------- merge partials + att_bias + residual + LayerNorm
template<int NS>
__global__ __launch_bounds__(256) void merge_ln(
    const unsigned short* __restrict__ op0, const unsigned short* __restrict__ op1,
    const unsigned short* __restrict__ op2, const unsigned short* __restrict__ op3,
    const float* __restrict__ ml, const float* __restrict__ x,
    const float* __restrict__ ab, const float* __restrict__ gam,
    const float* __restrict__ bet, float* __restrict__ out, int N){
  const int lane = threadIdx.x & 63;
  const long row = (long)blockIdx.x*4 + (threadIdx.x >> 6);
  const unsigned short* ops[4] = {op0, op1, op2, op3};
  float mm[NS], ll[NS];
  float M = -3.0e38f;
  #pragma unroll
  for (int i=0;i<NS;i++){
    float2 v = ((const float2*)ml)[(size_t)i*N + row];
    mm[i]=v.x; ll[i]=v.y;
    M = fmaxf(M, v.x);
  }
  float den = 0.f;
  float wgt[NS];
  #pragma unroll
  for (int i=0;i<NS;i++){ wgt[i] = __expf(mm[i]-M)*ll[i]; den += wgt[i]; }
  float invd = 1.f/den;
  float o0 = 0.f, o1 = 0.f;
  #pragma unroll
  for (int i=0;i<NS;i++){
    unsigned u = *(const unsigned*)&ops[i][row*CC + lane*2];
    float c = wgt[i]*invd;
    o0 += c * bf2f((unsigned short)(u & 0xffffu));
    o1 += c * bf2f((unsigned short)(u >> 16));
  }
  float2 xb = ((const float2*)(x + row*CC))[lane];
  float2 bb = ((const float2*)ab)[lane];
  float a0 = o0 + bb.x + xb.x;
  float a1 = o1 + bb.y + xb.y;
  float s = a0 + a1, ss = a0*a0 + a1*a1;
  #pragma unroll
  for (int off=32; off; off>>=1){ s += __shfl_xor(s,off); ss += __shfl_xor(ss,off); }
  float mu  = s * (1.f/128.f);
  float var = ss * (1.f/128.f) - mu*mu;
  float rstd = rsqrtf(var + 1e-5f);
  float2 gg = ((const float2*)gam)[lane];
  float2 b2 = ((const float2*)bet)[lane];
  float2 r;
  r.x = (a0 - mu)*rstd*gg.x + b2.x;
  r.y = (a1 - mu)*rstd*gg.y + b2.y;
  ((float2*)(out + row*CC))[lane] = r;
}

extern "C" void kernel_launch(void* const* d_in, const int* in_sizes, int n_in,
                              void* d_out, int out_size, void* d_ws, size_t ws_size,
                              hipStream_t stream) {
  const float* x   = (const float*)d_in[0];
  const int*   ei  = (const int*)d_in[1];
  const float* W1  = (const float*)d_in[3];
  const float* a_s1= (const float*)d_in[4];
  const float* a_d1= (const float*)d_in[5];
  const float* b1  = (const float*)d_in[6];
  const float* W2  = (const float*)d_in[7];
  const float* a_s2= (const float*)d_in[8];
  const float* a_d2= (const float*)d_in[9];
  const float* b2  = (const float*)d_in[10];
  const float* Wa  = (const float*)d_in[11];
  const float* ab  = (const float*)d_in[12];
  const float* g   = (const float*)d_in[13];
  const float* be  = (const float*)d_in[14];
  float* out = (float*)d_out;

  const int N = in_sizes[0] / CC;
  const int E = in_sizes[1] / 2;
  const size_t MB = 1024*1024;

  char* base = (char*)d_ws;
  // region map (overlaid by phase):
  // [0,8M):   GAT xw (f32)          -> later Qb bf16 [0,4M) + Hb bf16 [4,8M)
  // [8,16M):  GAT/attn h (f32)      -> later Opart splits 0,1 (bf16)
  // [16,20M): alpha+small (GAT)     -> later HTb bf16 [128][N]
  // [20,28M): Opart splits 2,3 (bf16, nsplit=4 only)
  // ml: 28M (ns=4) or 20M (ns=2)
  float* xw   = (float*)(base + 0);
  float* h    = (float*)(base + 8*MB);
  float* alpha= (float*)(base + 16*MB);
  float* as_  = (float*)(base + 16*MB + (size_t)(E+N)*4);
  float* ad_  = as_ + N;
  float* den  = ad_ + N;
  unsigned* emx = (unsigned*)(den + N);
  unsigned short* Qb  = (unsigned short*)(base + 0);
  unsigned short* Hb  = (unsigned short*)(base + 4*MB);
  unsigned short* HTb = (unsigned short*)(base + 16*MB);
  unsigned short* opLo= (unsigned short*)(base + 8*MB);
  unsigned short* opHi= (unsigned short*)(base + 20*MB);

  const size_t need4 = 28*MB + (size_t)4*N*2*sizeof(float);
  const int ns = (ws_size >= need4) ? 4 : 2;
  float* ml = (float*)(base + (ns == 4 ? 28*MB : 20*MB));

  dim3 B(256);
  const int gEN = (E + N + 255)/256;

  // ---- GAT layer 1
  gemm128<false,false><<<N/32, B, 0, stream>>>(x, W1, xw);
  rowdot2<<<N/4, B, 0, stream>>>(xw, a_s1, a_d1, as_, ad_);
  gat_init<<<(N+255)/256, B, 0, stream>>>(as_, ad_, emx, den, N);
  gat_edge_max<<<(E+255)/256, B, 0, stream>>>(ei, as_, ad_, emx, E);
  gat_alpha<<<gEN, B, 0, stream>>>(ei, as_, ad_, emx, den, alpha, E, N);
  gat_alpha_norm<<<gEN, B, 0, stream>>>(ei, den, alpha, E, N);
  gat_out_init<<<N/8, B, 0, stream>>>(xw, alpha, b1, h, E, N);
  gat_scatter<<<E/8, B, 0, stream>>>(ei, xw, alpha, h, E);

  // ---- GAT layer 2
  gemm128<true,false><<<N/32, B, 0, stream>>>(h, W2, xw);
  rowdot2<<<N/4, B, 0, stream>>>(xw, a_s2, a_d2, as_, ad_);
  gat_init<<<(N+255)/256, B, 0, stream>>>(as_, ad_, emx, den, N);
  gat_edge_max<<<(E+255)/256, B, 0, stream>>>(ei, as_, ad_, emx, E);
  gat_alpha<<<gEN, B, 0, stream>>>(ei, as_, ad_, emx, den, alpha, E, N);
  gat_alpha_norm<<<gEN, B, 0, stream>>>(ei, den, alpha, E, N);
  gat_out_init<<<N/8, B, 0, stream>>>(xw, alpha, b2, h, E, N);
  gat_scatter<<<E/8, B, 0, stream>>>(ei, xw, alpha, h, E);

  // ---- temporal attention (bf16 MFMA flash)
  gemm128<false,true><<<N/32, B, 0, stream>>>(h, Wa, Qb);      // q in bf16
  convert_ht<<<dim3(N/64, 2), B, 0, stream>>>(h, Hb, HTb, N);  // h -> bf16 + transpose
  attn_mfma<<<dim3(N/128, ns), B, 0, stream>>>(Qb, Hb, HTb, opLo, opHi, ml, N, ns);

  // ---- merge + att_bias + residual + LayerNorm
  if (ns == 4)
    merge_ln<4><<<N/4, B, 0, stream>>>(opLo, opLo + (size_t)N*CC, opHi, opHi + (size_t)N*CC,
                                       ml, x, ab, g, be, out, N);
  else
    merge_ln<2><<<N/4, B, 0, stream>>>(opLo, opLo + (size_t)N*CC, opLo, opLo,
                                       ml, x, ab, g, be, out, N);
}

// Round 3
// 641.430 us; speedup vs baseline: 8.8503x; 3.6322x over previous
//
#include <hip/hip_runtime.h>

#define CC 128

typedef __attribute__((ext_vector_type(8))) short bf16x8;
typedef __attribute__((ext_vector_type(4))) float f32x4;

static __device__ __forceinline__ float lrelu(float v){ return v > 0.f ? v : 0.2f*v; }
static __device__ __forceinline__ unsigned short f2bf(float f){
  unsigned u = __float_as_uint(f);
  unsigned r = (u + 0x7fffu + ((u >> 16) & 1u)) >> 16;
  return (unsigned short)r;
}
static __device__ __forceinline__ float bf2f(unsigned short s){
  return __uint_as_float(((unsigned)s) << 16);
}

// ---------------- GEMM: out[N,128] = (RELU?relu(in):in)[N,128] @ W[128,128]
template<bool RELU, bool OBF16>
__global__ __launch_bounds__(256) void gemm128(const float* __restrict__ in,
                                               const float* __restrict__ W,
                                               void* __restrict__ outv){
  __shared__ float4 xs4[32*33];
  const int tid = threadIdx.x;
  const long row0 = (long)blockIdx.x * 32;
  const float4* in4 = (const float4*)(in + row0*CC);
  #pragma unroll
  for (int i=0;i<4;i++){
    int f = tid + i*256;
    float4 v = in4[f];
    if (RELU){ v.x=fmaxf(v.x,0.f); v.y=fmaxf(v.y,0.f); v.z=fmaxf(v.z,0.f); v.w=fmaxf(v.w,0.f); }
    xs4[(f>>5)*33 + (f&31)] = v;
  }
  __syncthreads();
  const int tc = tid & 31;
  const int tr = tid >> 5;
  const float4* W4 = (const float4*)W;
  float acc[4][4] = {};
  #pragma unroll 2
  for (int kq=0; kq<32; kq++){
    float4 w0 = W4[(kq*4+0)*32 + tc];
    float4 w1 = W4[(kq*4+1)*32 + tc];
    float4 w2 = W4[(kq*4+2)*32 + tc];
    float4 w3 = W4[(kq*4+3)*32 + tc];
    #pragma unroll
    for (int i=0;i<4;i++){
      float4 xv = xs4[(tr*4+i)*33 + kq];
      acc[i][0] += xv.x*w0.x + xv.y*w1.x + xv.z*w2.x + xv.w*w3.x;
      acc[i][1] += xv.x*w0.y + xv.y*w1.y + xv.z*w2.y + xv.w*w3.y;
      acc[i][2] += xv.x*w0.z + xv.y*w1.z + xv.z*w2.z + xv.w*w3.z;
      acc[i][3] += xv.x*w0.w + xv.y*w1.w + xv.z*w2.w + xv.w*w3.w;
    }
  }
  if (OBF16){
    unsigned short* out = (unsigned short*)outv;
    #pragma unroll
    for (int i=0;i<4;i++){
      ushort4 o; o.x=f2bf(acc[i][0]); o.y=f2bf(acc[i][1]); o.z=f2bf(acc[i][2]); o.w=f2bf(acc[i][3]);
      *(ushort4*)&out[(row0 + tr*4 + i)*CC + tc*4] = o;
    }
  } else {
    float4* out4 = (float4*)((float*)outv + row0*CC);
    #pragma unroll
    for (int i=0;i<4;i++)
      out4[(tr*4+i)*32 + tc] = make_float4(acc[i][0],acc[i][1],acc[i][2],acc[i][3]);
  }
}

// ---------------- per-row dot with two vectors
__global__ __launch_bounds__(256) void rowdot2(const float* __restrict__ xw,
                                               const float* __restrict__ a1,
                                               const float* __restrict__ a2,
                                               float* __restrict__ as_, float* __restrict__ ad_){
  const int lane = threadIdx.x & 63;
  const long row = (long)blockIdx.x*4 + (threadIdx.x >> 6);
  float2 v  = ((const float2*)(xw + row*CC))[lane];
  float2 w1 = ((const float2*)a1)[lane];
  float2 w2 = ((const float2*)a2)[lane];
  float s1 = v.x*w1.x + v.y*w1.y;
  float s2 = v.x*w2.x + v.y*w2.y;
  #pragma unroll
  for (int off=32; off; off>>=1){
    s1 += __shfl_xor(s1, off);
    s2 += __shfl_xor(s2, off);
  }
  if (lane==0){ as_[row]=s1; ad_[row]=s2; }
}

// ---------------- CSR build (edge_index is identical for both layers)
__global__ void zero_int(int* __restrict__ p, int n){
  int i = blockIdx.x*256 + threadIdx.x;
  if (i < n) p[i] = 0;
}
__global__ void csr_hist(const int* __restrict__ ei, int* __restrict__ deg, int E){
  int e = blockIdx.x*256 + threadIdx.x;
  if (e < E) atomicAdd(&deg[ei[E + e]], 1);
}
// single block, 256 threads: exclusive scan of deg[0..N) -> rowptr, cursor
__global__ __launch_bounds__(256) void csr_scan(const int* __restrict__ deg,
                                                int* __restrict__ rowptr,
                                                int* __restrict__ cursor, int N){
  __shared__ int part[257];
  const int t = threadIdx.x;
  const int per = N / 256;          // 64
  const int base = t*per;
  int s = 0;
  for (int j=0;j<per;j++) s += deg[base+j];
  part[t+1] = s;
  if (t==0) part[0] = 0;
  __syncthreads();
  if (t==0){
    for (int i=1;i<=256;i++) part[i] += part[i-1];
  }
  __syncthreads();
  int run = part[t];
  for (int j=0;j<per;j++){
    rowptr[base+j] = run;
    cursor[base+j] = run;
    run += deg[base+j];
  }
  if (t==255) rowptr[N] = run;
}
__global__ void csr_fill(const int* __restrict__ ei, int* __restrict__ cursor,
                         int* __restrict__ csrc, int E){
  int e = blockIdx.x*256 + threadIdx.x;
  if (e < E){
    int d = ei[E + e];
    int slot = atomicAdd(&cursor[d], 1);
    csrc[slot] = ei[e];
  }
}

// ---------------- fused GAT: online segment-softmax + aggregate, no atomics
// one wave per dst node; lane owns 2 channels (float2)
__global__ __launch_bounds__(256) void gat_gather(
    const int* __restrict__ rowptr, const int* __restrict__ csrc,
    const float* __restrict__ as_, const float* __restrict__ ad_,
    const float* __restrict__ xw, const float* __restrict__ b,
    float* __restrict__ out, int N){
  const int lane = threadIdx.x & 63;
  const int dst = blockIdx.x*4 + (threadIdx.x >> 6);
  const float adv = ad_[dst];
  // self loop init
  float m = lrelu(as_[dst] + adv);
  float l = 1.f;
  float2 acc = ((const float2*)(xw + (size_t)dst*CC))[lane];
  const int kb = rowptr[dst], ke = rowptr[dst+1];
  int k = kb;
  int s_cur = 0; float a_cur = 0.f;
  if (k < ke){ s_cur = csrc[k]; a_cur = as_[s_cur]; }
  while (k < ke){
    int k1 = k + 1;
    int s_nxt = 0; float a_nxt = 0.f;
    if (k1 < ke){ s_nxt = csrc[k1]; a_nxt = as_[s_nxt]; }   // prefetch
    float2 v = ((const float2*)(xw + (size_t)s_cur*CC))[lane];
    float e = lrelu(a_cur + adv);
    float mn = fmaxf(m, e);
    float fr = __expf(m - mn);
    float p  = __expf(e - mn);
    acc.x = acc.x*fr + p*v.x;
    acc.y = acc.y*fr + p*v.y;
    l = l*fr + p;
    m = mn;
    s_cur = s_nxt; a_cur = a_nxt; k = k1;
  }
  float inv = 1.f / l;
  float2 bb = ((const float2*)b)[lane];
  float2 r; r.x = acc.x*inv + bb.x; r.y = acc.y*inv + bb.y;
  ((float2*)(out + (size_t)dst*CC))[lane] = r;
}

// ---------------- h (f32) -> Hb (bf16 row-major) + HTb (bf16 transposed [C][N])
__global__ __launch_bounds__(256) void convert_ht(const float* __restrict__ h,
                                                  unsigned short* __restrict__ Hb,
                                                  unsigned short* __restrict__ HTb, int N){
  __shared__ unsigned short t[64][72];
  const int tid = threadIdx.x;
  const int n0 = blockIdx.x*64, c0 = blockIdx.y*64;
  #pragma unroll
  for (int i=0;i<4;i++){
    int f = tid + i*256;
    int row = f>>4, c4 = f&15;
    float4 v = *(const float4*)&h[(size_t)(n0+row)*CC + c0 + c4*4];
    ushort4 b; b.x=f2bf(v.x); b.y=f2bf(v.y); b.z=f2bf(v.z); b.w=f2bf(v.w);
    *(ushort4*)&Hb[(size_t)(n0+row)*CC + c0 + c4*4] = b;
    *(ushort4*)&t[row][c4*4] = b;
  }
  __syncthreads();
  #pragma unroll
  for (int i=0;i<4;i++){
    int f = tid + i*256;
    int c = f>>4, n4 = f&15;
    ushort4 b;
    b.x = t[n4*4+0][c]; b.y = t[n4*4+1][c]; b.z = t[n4*4+2][c]; b.w = t[n4*4+3][c];
    *(ushort4*)&HTb[(size_t)(c0+c)*N + n0 + n4*4] = b;
  }
}

// ---------------- MFMA flash attention (bf16), KV-split with normalized partials
__global__ __launch_bounds__(256,2) void attn_mfma(
    const unsigned short* __restrict__ Qb, const unsigned short* __restrict__ Hb,
    const unsigned short* __restrict__ HTb,
    unsigned short* __restrict__ opLo, unsigned short* __restrict__ opHi,
    float* __restrict__ ml, int N, int nsplit){
  __shared__ uint4 SH[16*64];
  __shared__ uint4 STl[16*64];
  __shared__ uint4 PT[4*4*64];

  const int tid = threadIdx.x;
  const int lane = tid & 63, w = tid >> 6;
  const int g = lane >> 4, c15 = lane & 15;
  const int qb0 = blockIdx.x * 128;
  const int split = blockIdx.y;
  const int keysPerSplit = N / nsplit;
  const int key00 = split * keysPerSplit;
  const int ntiles = keysPerSplit >> 6;
  const float RS = 0.088388347648318447f;

  bf16x8 qf[2][4];
  const int qrow_base = qb0 + w*32;
  #pragma unroll
  for (int qt=0; qt<2; qt++)
    #pragma unroll
    for (int ks=0; ks<4; ks++)
      qf[qt][ks] = *(const bf16x8*)&Qb[(size_t)(qrow_base + qt*16 + c15)*CC + ks*32 + g*8];

  f32x4 zero4 = {0.f,0.f,0.f,0.f};
  f32x4 acc_o[8][2];
  #pragma unroll
  for (int a=0;a<8;a++){ acc_o[a][0]=zero4; acc_o[a][1]=zero4; }
  float m_[2] = {-3.0e38f, -3.0e38f};
  float l_[2] = {0.f, 0.f};

  int shU[4], stU[4];
  #pragma unroll
  for (int i=0;i<4;i++){
    int f = tid + i*256;
    int key = f>>4, c8 = f&15;
    shU[i] = ((key>>4)*4 + (c8>>2))*64 + (c8&3)*16 + (key&15);
    int c = f>>3, k8 = f&7;
    stU[i] = ((c>>4)*2 + (k8>>2))*64 + (k8&3)*16 + (c&15);
  }

  uint4 G[8];
  {
    const unsigned short* hb = Hb + (size_t)key00*CC;
    const unsigned short* ht = HTb + key00;
    #pragma unroll
    for (int i=0;i<4;i++){
      int f = tid + i*256;
      G[i]   = *(const uint4*)&hb[(size_t)(f>>4)*CC + (f&15)*8];
      G[4+i] = *(const uint4*)&ht[(size_t)(f>>3)*N + (f&7)*8];
    }
  }

  for (int t=0; t<ntiles; t++){
    __syncthreads();
    #pragma unroll
    for (int i=0;i<4;i++) SH[shU[i]]  = G[i];
    #pragma unroll
    for (int i=0;i<4;i++) STl[stU[i]] = G[4+i];
    if (t+1 < ntiles){
      const unsigned short* hb = Hb + (size_t)(key00 + (t+1)*64)*CC;
      const unsigned short* ht = HTb + key00 + (t+1)*64;
      #pragma unroll
      for (int i=0;i<4;i++){
        int f = tid + i*256;
        G[i]   = *(const uint4*)&hb[(size_t)(f>>4)*CC + (f&15)*8];
        G[4+i] = *(const uint4*)&ht[(size_t)(f>>3)*N + (f&7)*8];
      }
    }
    __syncthreads();

    f32x4 accs[4][2];
    #pragma unroll
    for (int kt=0; kt<4; kt++){ accs[kt][0]=zero4; accs[kt][1]=zero4; }
    #pragma unroll
    for (int kt=0; kt<4; kt++)
      #pragma unroll
      for (int ks=0; ks<4; ks++){
        bf16x8 hf = *(const bf16x8*)&SH[(kt*4+ks)*64 + lane];
        accs[kt][0] = __builtin_amdgcn_mfma_f32_16x16x32_bf16(hf, qf[0][ks], accs[kt][0], 0,0,0);
        accs[kt][1] = __builtin_amdgcn_mfma_f32_16x16x32_bf16(hf, qf[1][ks], accs[kt][1], 0,0,0);
      }

    float fr[2];
    #pragma unroll
    for (int qt=0; qt<2; qt++){
      float tm = -3.0e38f;
      #pragma unroll
      for (int kt=0; kt<4; kt++)
        #pragma unroll
        for (int r=0; r<4; r++) tm = fmaxf(tm, accs[kt][qt][r]);
      tm *= RS;
      tm = fmaxf(tm, __shfl_xor(tm, 16));
      tm = fmaxf(tm, __shfl_xor(tm, 32));
      float mn = fmaxf(m_[qt], tm);
      fr[qt] = __expf(m_[qt] - mn);
      m_[qt] = mn;
      float ps = 0.f;
      #pragma unroll
      for (int kt=0; kt<4; kt++)
        #pragma unroll
        for (int r=0; r<4; r++){
          float p = __expf(accs[kt][qt][r]*RS - mn);
          accs[kt][qt][r] = p;
          ps += p;
        }
      ps += __shfl_xor(ps, 16);
      ps += __shfl_xor(ps, 32);
      l_[qt] = l_[qt]*fr[qt] + ps;
    }
    #pragma unroll
    for (int a=0;a<8;a++){
      #pragma unroll
      for (int qt=0; qt<2; qt++){
        acc_o[a][qt][0]*=fr[qt]; acc_o[a][qt][1]*=fr[qt];
        acc_o[a][qt][2]*=fr[qt]; acc_o[a][qt][3]*=fr[qt];
      }
    }

    unsigned short* pt16 = (unsigned short*)&PT[w*256];
    #pragma unroll
    for (int kt=0; kt<4; kt++)
      #pragma unroll
      for (int qt=0; qt<2; qt++){
        ushort4 pk;
        pk.x = f2bf(accs[kt][qt][0]); pk.y = f2bf(accs[kt][qt][1]);
        pk.z = f2bf(accs[kt][qt][2]); pk.w = f2bf(accs[kt][qt][3]);
        int addr = ((kt>>1)*2 + qt)*512 + (((kt&1)*2 + (g>>1))*16 + c15)*8 + (g&1)*4;
        *(ushort4*)&pt16[addr] = pk;
      }
    bf16x8 ptf[2][2];
    const uint4* ptv = &PT[w*256];
    #pragma unroll
    for (int ks2=0; ks2<2; ks2++)
      #pragma unroll
      for (int qt=0; qt<2; qt++)
        ptf[ks2][qt] = *(const bf16x8*)&ptv[(ks2*2+qt)*64 + lane];

    #pragma unroll
    for (int ct2=0; ct2<8; ct2++)
      #pragma unroll
      for (int ks2=0; ks2<2; ks2++){
        bf16x8 hf = *(const bf16x8*)&STl[(ct2*2+ks2)*64 + lane];
        acc_o[ct2][0] = __builtin_amdgcn_mfma_f32_16x16x32_bf16(hf, ptf[ks2][0], acc_o[ct2][0], 0,0,0);
        acc_o[ct2][1] = __builtin_amdgcn_mfma_f32_16x16x32_bf16(hf, ptf[ks2][1], acc_o[ct2][1], 0,0,0);
      }
  }

  unsigned short* opBase = (split < 2) ? (opLo + (size_t)split*N*CC)
                                       : (opHi + (size_t)(split-2)*N*CC);
  #pragma unroll
  for (int qt=0; qt<2; qt++){
    float inv = 1.f / l_[qt];
    int qrow = qrow_base + qt*16 + c15;
    #pragma unroll
    for (int ct2=0; ct2<8; ct2++){
      ushort4 o;
      o.x = f2bf(acc_o[ct2][qt][0]*inv); o.y = f2bf(acc_o[ct2][qt][1]*inv);
      o.z = f2bf(acc_o[ct2][qt][2]*inv); o.w = f2bf(acc_o[ct2][qt][3]*inv);
      *(ushort4*)&opBase[(size_t)qrow*CC + ct2*16 + g*4] = o;
    }
    if (g == 0)
      ((float2*)ml)[(size_t)split*N + qrow] = make_float2(m_[qt], l_[qt]);
  }
}

// ---------------- merge partials + att_bias + residual + LayerNorm
template<int NS>
__global__ __launch_bounds__(256) void merge_ln(
    const unsigned short* __restrict__ op0, const unsigned short* __restrict__ op1,
    const unsigned short* __restrict__ op2, const unsigned short* __restrict__ op3,
    const float* __restrict__ ml, const float* __restrict__ x,
    const float* __restrict__ ab, const float* __restrict__ gam,
    const float* __restrict__ bet, float* __restrict__ out, int N){
  const int lane = threadIdx.x & 63;
  const long row = (long)blockIdx.x*4 + (threadIdx.x >> 6);
  const unsigned short* ops[4] = {op0, op1, op2, op3};
  float mm[NS], ll[NS];
  float M = -3.0e38f;
  #pragma unroll
  for (int i=0;i<NS;i++){
    float2 v = ((const float2*)ml)[(size_t)i*N + row];
    mm[i]=v.x; ll[i]=v.y;
    M = fmaxf(M, v.x);
  }
  float den = 0.f;
  float wgt[NS];
  #pragma unroll
  for (int i=0;i<NS;i++){ wgt[i] = __expf(mm[i]-M)*ll[i]; den += wgt[i]; }
  float invd = 1.f/den;
  float o0 = 0.f, o1 = 0.f;
  #pragma unroll
  for (int i=0;i<NS;i++){
    unsigned u = *(const unsigned*)&ops[i][row*CC + lane*2];
    float c = wgt[i]*invd;
    o0 += c * bf2f((unsigned short)(u & 0xffffu));
    o1 += c * bf2f((unsigned short)(u >> 16));
  }
  float2 xb = ((const float2*)(x + row*CC))[lane];
  float2 bb = ((const float2*)ab)[lane];
  float a0 = o0 + bb.x + xb.x;
  float a1 = o1 + bb.y + xb.y;
  float s = a0 + a1, ss = a0*a0 + a1*a1;
  #pragma unroll
  for (int off=32; off; off>>=1){ s += __shfl_xor(s,off); ss += __shfl_xor(ss,off); }
  float mu  = s * (1.f/128.f);
  float var = ss * (1.f/128.f) - mu*mu;
  float rstd = rsqrtf(var + 1e-5f);
  float2 gg = ((const float2*)gam)[lane];
  float2 b2 = ((const float2*)bet)[lane];
  float2 r;
  r.x = (a0 - mu)*rstd*gg.x + b2.x;
  r.y = (a1 - mu)*rstd*gg.y + b2.y;
  ((float2*)(out + row*CC))[lane] = r;
}

extern "C" void kernel_launch(void* const* d_in, const int* in_sizes, int n_in,
                              void* d_out, int out_size, void* d_ws, size_t ws_size,
                              hipStream_t stream) {
  const float* x   = (const float*)d_in[0];
  const int*   ei  = (const int*)d_in[1];
  const float* W1  = (const float*)d_in[3];
  const float* a_s1= (const float*)d_in[4];
  const float* a_d1= (const float*)d_in[5];
  const float* b1  = (const float*)d_in[6];
  const float* W2  = (const float*)d_in[7];
  const float* a_s2= (const float*)d_in[8];
  const float* a_d2= (const float*)d_in[9];
  const float* b2  = (const float*)d_in[10];
  const float* Wa  = (const float*)d_in[11];
  const float* ab  = (const float*)d_in[12];
  const float* g   = (const float*)d_in[13];
  const float* be  = (const float*)d_in[14];
  float* out = (float*)d_out;

  const int N = in_sizes[0] / CC;
  const int E = in_sizes[1] / 2;
  const size_t MB = 1024*1024;
  const size_t KB = 1024;

  char* base = (char*)d_ws;
  // GAT phase:   [0,8M) xw f32 | [8,16M) h f32 | [16,18M) csrc | [18M..) csr meta + as/ad
  // attn phase:  [0,4M) Qb | [4,8M) Hb | [8,16M) opLo | [16,20M) HTb | [20,28M) opHi | 28M ml
  float* xw   = (float*)(base + 0);
  float* h    = (float*)(base + 8*MB);
  int* csrc   = (int*)(base + 16*MB);
  int* rowptr = (int*)(base + 18*MB);
  int* cursor = (int*)(base + 18*MB + 128*KB);
  int* deg    = (int*)(base + 18*MB + 256*KB);
  float* as_  = (float*)(base + 18*MB + 384*KB);
  float* ad_  = (float*)(base + 18*MB + 512*KB);
  unsigned short* Qb  = (unsigned short*)(base + 0);
  unsigned short* Hb  = (unsigned short*)(base + 4*MB);
  unsigned short* HTb = (unsigned short*)(base + 16*MB);
  unsigned short* opLo= (unsigned short*)(base + 8*MB);
  unsigned short* opHi= (unsigned short*)(base + 20*MB);

  const size_t need4 = 28*MB + (size_t)4*N*2*sizeof(float);
  const int ns = (ws_size >= need4) ? 4 : 2;
  float* ml = (float*)(base + (ns == 4 ? 28*MB : 20*MB));

  dim3 B(256);

  // ---- CSR build (once; shared by both GAT layers)
  zero_int<<<(N+255)/256, B, 0, stream>>>(deg, N);
  csr_hist<<<(E+255)/256, B, 0, stream>>>(ei, deg, E);
  csr_scan<<<1, B, 0, stream>>>(deg, rowptr, cursor, N);
  csr_fill<<<(E+255)/256, B, 0, stream>>>(ei, cursor, csrc, E);

  // ---- GAT layer 1: h = segsoftmax-aggregate(xw) + b1
  gemm128<false,false><<<N/32, B, 0, stream>>>(x, W1, xw);
  rowdot2<<<N/4, B, 0, stream>>>(xw, a_s1, a_d1, as_, ad_);
  gat_gather<<<N/4, B, 0, stream>>>(rowptr, csrc, as_, ad_, xw, b1, h, N);

  // ---- GAT layer 2 (relu fused into gemm)
  gemm128<true,false><<<N/32, B, 0, stream>>>(h, W2, xw);
  rowdot2<<<N/4, B, 0, stream>>>(xw, a_s2, a_d2, as_, ad_);
  gat_gather<<<N/4, B, 0, stream>>>(rowptr, csrc, as_, ad_, xw, b2, h, N);

  // ---- temporal attention (bf16 MFMA flash)
  gemm128<false,true><<<N/32, B, 0, stream>>>(h, Wa, Qb);
  convert_ht<<<dim3(N/64, 2), B, 0, stream>>>(h, Hb, HTb, N);
  attn_mfma<<<dim3(N/128, ns), B, 0, stream>>>(Qb, Hb, HTb, opLo, opHi, ml, N, ns);

  // ---- merge + att_bias + residual + LayerNorm
  if (ns == 4)
    merge_ln<4><<<N/4, B, 0, stream>>>(opLo, opLo + (size_t)N*CC, opHi, opHi + (size_t)N*CC,
                                       ml, x, ab, g, be, out, N);
  else
    merge_ln<2><<<N/4, B, 0, stream>>>(opLo, opLo + (size_t)N*CC, opLo, opLo,
                                       ml, x, ab, g, be, out, N);
}